// Round 1
// baseline (381.590 us; speedup 1.0000x reference)
//
#include <hip/hip_runtime.h>

// ---- problem constants ----
#define TT   512
#define BI   12
#define HH   50
#define BB   8     // batch per block
#define BTOT 2048
#define LOG2E 1.4426950408889634f

// R10 = R9 (397 us) with two latency-chain cuts, structure untouched:
//  - layer-1 MFMA accumulation split into two independent chains
//    (acc0/acc0b, acc1/acc1b) + one f4 add: dependent-MFMA depth 4 -> 2
//    on the slowest (layer-1, 2-tile) waves that define barrier arrival.
//  - x prefetch distance 1 -> 2 steps ("xhold"): x[t+1] is loaded in
//    step t-1 and stored to LDS at the TOP of step t, so the vmcnt wait
//    can never land on the pre-barrier path even on HBM-miss (~900 cy).
// Layout (verified R5-R9): row r = u*4+gate -> each lane's f4 acc holds all
// 4 gates of one (unit,batch); cell update fully in-register. B = [x;h] in
// LDS fragment order [k>>3][n][k&7]; ping-pong parities; one barrier/step;
// layers software-pipelined by one step (exact): t: l0->h0[t], l1->h1[t-1].
// Trans-bundle optimality: bundles/CU-step = (units x batch)/64 requires
// tiles/wave x 4 x BB = 64 -> the 16-wave / BB=8 / 2-tile config is the
// unique optimum (R7's 2-block variant doubled trans and regressed).

typedef _Float16 half8 __attribute__((ext_vector_type(8)));
typedef float    f4    __attribute__((ext_vector_type(4)));

__device__ __forceinline__ float sigm_(float v) {
    return __builtin_amdgcn_rcpf(1.f + __builtin_amdgcn_exp2f(v * (-LOG2E)));
}
__device__ __forceinline__ float tanh_(float v) {
    return 1.f - 2.f * __builtin_amdgcn_rcpf(1.f + __builtin_amdgcn_exp2f(v * (2.f * LOG2E)));
}
// lanes with (lane&15)<8 keep a0; lanes with (lane&15)>=8 take a1 from
// lane^8 (DPP row_ror:8 = 0x128, banks 2,3 -> bank_mask 0xC). One VALU op.
__device__ __forceinline__ float dppmerge_(float a0, float a1) {
    int r = __builtin_amdgcn_update_dpp(__builtin_bit_cast(int, a0),
                                        __builtin_bit_cast(int, a1),
                                        0x128, 0xF, 0xC, false);
    return __builtin_bit_cast(float, r);
}

__launch_bounds__(1024)
__global__ void lstm2_kernel(const float* __restrict__ x,
                             const float* __restrict__ w_ih0, const float* __restrict__ w_hh0,
                             const float* __restrict__ b_ih0, const float* __restrict__ b_hh0,
                             const float* __restrict__ w_ih1, const float* __restrict__ w_hh1,
                             const float* __restrict__ b_ih1, const float* __restrict__ b_hh1,
                             const float* __restrict__ w_out, const float* __restrict__ b_out,
                             float* __restrict__ out)
{
    const int tid   = threadIdx.x;
    const int wv    = tid >> 6;          // 0..15
    const int lane  = tid & 63;
    const int layer = wv >> 3;           // 0 or 1
    const int w8    = wv & 7;
    const int b0    = blockIdx.x * BB;
    // 13 M-tiles per layer over 8 waves: waves 0-4 take 2, waves 5-7 take 1.
    const int t0     = (w8 < 5) ? 2 * w8 : (5 + w8);
    const int ntiles = (w8 < 5) ? 2 : 1;

    __shared__ __align__(16) _Float16 B0s[2][64  * 16];
    __shared__ __align__(16) _Float16 B1s[2][128 * 16];

    // ---- step-invariant A fragments (weights, fragment layout) ----
    const int m = lane & 15;
    const int q = lane >> 4;
    half8 af[2][4];
    #pragma unroll
    for (int s = 0; s < 2; s++) {
        #pragma unroll
        for (int kb = 0; kb < 4; kb++) {
            #pragma unroll
            for (int j = 0; j < 8; j++) {
                float v = 0.f;
                if (s < ntiles && (layer == 1 || kb < 2)) {
                    const int T  = t0 + s;
                    const int u  = T * 4 + (m >> 2);
                    const int g  = m & 3;
                    const int kg = kb * 32 + q * 8 + j;
                    if (u < HH) {
                        const int r = g * HH + u;
                        if (layer == 0) {
                            if      (kg < 12)  v = w_ih0[r * BI + kg];
                            else if (kg < 62)  v = w_hh0[r * HH + (kg - 12)];
                            else if (kg == 62) v = b_ih0[r] + b_hh0[r];
                        } else {
                            if      (kg < 50)  v = w_ih1[r * HH + kg];
                            else if (kg < 64)  v = 0.f;
                            else if (kg < 114) v = w_hh1[r * HH + (kg - 64)];
                            else if (kg == 114) v = b_ih1[r] + b_hh1[r];
                        }
                    }
                }
                af[s][kb][j] = (_Float16)v;
            }
        }
    }

    // ---- init LDS ----
    for (int i = tid; i < 2 * 64 * 16;  i += 1024) (&B0s[0][0])[i] = (_Float16)0.f;
    for (int i = tid; i < 2 * 128 * 16; i += 1024) (&B1s[0][0])[i] = (_Float16)0.f;
    __syncthreads();
    if (tid < 16) {                       // bias (ones) rows, both parities
        B0s[0][7  * 128 + tid * 8 + 6] = (_Float16)1.f;
        B0s[1][7  * 128 + tid * 8 + 6] = (_Float16)1.f;
        B1s[0][14 * 128 + tid * 8 + 2] = (_Float16)1.f;
        B1s[1][14 * 128 + tid * 8 + 2] = (_Float16)1.f;
    }
    const int xb = tid / 12, xi = tid - xb * 12;           // loop-invariant
    const int xoff = (xi >> 3) * 128 + xb * 8 + (xi & 7);
    const size_t xbase = ((size_t)(b0 + xb) * TT) * BI + xi;
    if (tid < 96)                          // x[0] -> parity 0
        B0s[0][xoff] = (_Float16)x[xbase];
    __syncthreads();

    // ---- merged update role: lane owns (u_m, bcol) ----
    const int n16  = lane & 15;
    const int slot = n16 >> 3;            // 0: own acc0; 1: partner's acc1
    const int bcol = n16 & 7;
    const int u_m  = (t0 + slot) * 4 + q;
    const bool wvalid = (u_m < HH) && (slot == 0 || ntiles == 2);
    float cm = 0.f;                        // cell state for (u_m, bcol)

    // ---- per-parity pointers (constant-indexed -> folded at compile time) ----
    const _Float16* rdA[2] = { (layer ? &B1s[0][0] : &B0s[0][0]) + lane * 8,
                               (layer ? &B1s[1][0] : &B0s[1][0]) + lane * 8 };
    const int k0 = 12 + u_m;              // h0 row in B0
    const int k1 = 64 + u_m;              // h1 row in B1
    const int offA = layer ? ((k1 >> 3) * 128 + bcol * 8 + (k1 & 7))
                           : ((k0 >> 3) * 128 + bcol * 8 + (k0 & 7));
    const int offB = (u_m >> 3) * 128 + bcol * 8 + (u_m & 7);   // h0 row in B1
    _Float16* wAp[2] = { (layer ? &B1s[0][0] : &B0s[0][0]) + offA,
                         (layer ? &B1s[1][0] : &B0s[1][0]) + offA };
    _Float16* wBp[2] = { &B1s[0][0] + offB, &B1s[1][0] + offB };
    _Float16* xdp[2] = { &B0s[0][0] + xoff, &B0s[1][0] + xoff };

    // x stream, 2-step-ahead: xhold carries x[t+1] across a full step.
    const float* xq = x + xbase + BI;     // points at x[1]
    float xhold = 0.f;
    if (tid < 96) xhold = *xq;            // preload x[1]
    xq += BI;                             // points at x[2]

// One timestep at compile-time parity P. DOL0/DOL1: layer activity
// (peel boundaries). DOST: store xhold (=x[t+1]) into parity 1-P.
// DOLD: issue load of x[t+2] (consumed next step).
#define STEP(P, DOL0, DOL1, DOST, DOLD)                                       \
  {                                                                           \
    float xnew = 0.f;                                                         \
    if ((DOLD) && tid < 96) xnew = *xq;                                       \
    if ((DOST) && tid < 96) *xdp[1 - (P)] = (_Float16)xhold;                  \
    if ((layer == 0) ? (DOL0) : (DOL1)) {                                     \
      f4 acc0 = {0.f, 0.f, 0.f, 0.f}, acc1 = {0.f, 0.f, 0.f, 0.f};            \
      const _Float16* Bp = rdA[P];                                            \
      if (layer == 0) {                                                       \
        const half8 bf0 = *(const half8*)(Bp);                                \
        const half8 bf1 = *(const half8*)(Bp + 512);                          \
        acc0 = __builtin_amdgcn_mfma_f32_16x16x32_f16(af[0][0], bf0, acc0, 0, 0, 0); \
        if (ntiles > 1)                                                       \
          acc1 = __builtin_amdgcn_mfma_f32_16x16x32_f16(af[1][0], bf0, acc1, 0, 0, 0); \
        acc0 = __builtin_amdgcn_mfma_f32_16x16x32_f16(af[0][1], bf1, acc0, 0, 0, 0); \
        if (ntiles > 1)                                                       \
          acc1 = __builtin_amdgcn_mfma_f32_16x16x32_f16(af[1][1], bf1, acc1, 0, 0, 0); \
      } else {                                                                \
        f4 acc0b = {0.f, 0.f, 0.f, 0.f}, acc1b = {0.f, 0.f, 0.f, 0.f};        \
        const half8 bf0 = *(const half8*)(Bp);                                \
        const half8 bf1 = *(const half8*)(Bp + 512);                          \
        const half8 bf2 = *(const half8*)(Bp + 1024);                         \
        const half8 bf3 = *(const half8*)(Bp + 1536);                         \
        acc0  = __builtin_amdgcn_mfma_f32_16x16x32_f16(af[0][0], bf0, acc0,  0, 0, 0); \
        if (ntiles > 1)                                                       \
          acc1  = __builtin_amdgcn_mfma_f32_16x16x32_f16(af[1][0], bf0, acc1,  0, 0, 0); \
        acc0b = __builtin_amdgcn_mfma_f32_16x16x32_f16(af[0][1], bf1, acc0b, 0, 0, 0); \
        if (ntiles > 1)                                                       \
          acc1b = __builtin_amdgcn_mfma_f32_16x16x32_f16(af[1][1], bf1, acc1b, 0, 0, 0); \
        acc0  = __builtin_amdgcn_mfma_f32_16x16x32_f16(af[0][2], bf2, acc0,  0, 0, 0); \
        if (ntiles > 1)                                                       \
          acc1  = __builtin_amdgcn_mfma_f32_16x16x32_f16(af[1][2], bf2, acc1,  0, 0, 0); \
        acc0b = __builtin_amdgcn_mfma_f32_16x16x32_f16(af[0][3], bf3, acc0b, 0, 0, 0); \
        if (ntiles > 1)                                                       \
          acc1b = __builtin_amdgcn_mfma_f32_16x16x32_f16(af[1][3], bf3, acc1b, 0, 0, 0); \
        acc0 += acc0b;                                                        \
        acc1 += acc1b;                                                        \
      }                                                                       \
      f4 am;                                                                  \
      _Pragma("unroll")                                                       \
      for (int i = 0; i < 4; i++) am[i] = dppmerge_(acc0[i], acc1[i]);        \
      const float iv = sigm_(am[0]);                                          \
      const float fv = sigm_(am[1]);                                          \
      const float gv = tanh_(am[2]);                                          \
      const float ov = sigm_(am[3]);                                          \
      cm = fv * cm + iv * gv;                                                 \
      const float h = ov * tanh_(cm);                                         \
      if (wvalid) {                                                           \
        const _Float16 hh = (_Float16)h;                                      \
        *wAp[1 - (P)] = hh;                                                   \
        if (layer == 0) *wBp[1 - (P)] = hh;                                   \
      }                                                                       \
    }                                                                         \
    if (DOLD) { xhold = xnew; xq += BI; }                                     \
    __syncthreads();                                                          \
  }

    STEP(0, 1, 0, 1, 1)                   // t = 0   (l0 only; store x[1], load x[2])
    STEP(1, 1, 1, 1, 1)                   // t = 1
    #pragma unroll 1
    for (int it = 0; it < 254; ++it) {    // t = 2 .. 509
        STEP(0, 1, 1, 1, 1)
        STEP(1, 1, 1, 1, 1)
    }
    STEP(0, 1, 1, 1, 0)                   // t = 510 (store x[511], no more loads)
    STEP(1, 1, 1, 0, 0)                   // t = 511
    STEP(0, 0, 1, 0, 0)                   // t = 512 (l1 only)
#undef STEP

    // ---- epilogue: sigmoid(h1[TT-1] . w_out + b_out); h1[TT-1] in parity 1 ----
    if (tid < BB) {
        float s = b_out[0];
        #pragma unroll
        for (int u = 0; u < HH; u++) {
            const int kk = 64 + u;
            s += w_out[u] * (float)B1s[1][(kk >> 3) * 128 + tid * 8 + (kk & 7)];
        }
        out[b0 + tid] = sigm_(s);
    }
}

extern "C" void kernel_launch(void* const* d_in, const int* in_sizes, int n_in,
                              void* d_out, int out_size, void* d_ws, size_t ws_size,
                              hipStream_t stream) {
    const float* x     = (const float*)d_in[0];
    const float* w_ih0 = (const float*)d_in[1];
    const float* w_hh0 = (const float*)d_in[2];
    const float* b_ih0 = (const float*)d_in[3];
    const float* b_hh0 = (const float*)d_in[4];
    const float* w_ih1 = (const float*)d_in[5];
    const float* w_hh1 = (const float*)d_in[6];
    const float* b_ih1 = (const float*)d_in[7];
    const float* b_hh1 = (const float*)d_in[8];
    const float* w_out = (const float*)d_in[9];
    const float* b_out = (const float*)d_in[10];
    float* out = (float*)d_out;

    dim3 grid(BTOT / BB);   // 256 blocks -> 1 per CU
    dim3 block(1024);       // 16 waves: 8 layer-0 + 8 layer-1
    lstm2_kernel<<<grid, block, 0, stream>>>(x, w_ih0, w_hh0, b_ih0, b_hh0,
                                             w_ih1, w_hh1, b_ih1, b_hh1,
                                             w_out, b_out, out);
}

// Round 2
// 368.747 us; speedup vs baseline: 1.0348x; 1.0348x over previous
//
#include <hip/hip_runtime.h>

// ---- problem constants ----
#define TT   512
#define BI   12
#define HH   50
#define BB   8     // batch per block
#define BTOT 2048
#define LOG2E 1.4426950408889634f

// R11 = R10 (381 us; VALUBusy 58%, MfmaUtil 26% -> issue-bound) minus
// removable VALU fat, structure untouched:
//  - activation input scales (-log2e for i,f,o; +2log2e for g) folded into
//    the f16 weight/bias fragments at build time: MFMA output IS the exp2
//    argument -> 4 v_mul/lane-step gone, activation chain 1 op shorter.
//  - persistent fzero f4 as the MFMA C operand (D!=C): no per-step
//    accumulator zero-init movs (was up to 16/step on layer-1 waves).
//  - unified h0 buffer: B0s K-space reordered to [h0 0-49 | x 50-61 |
//    bias 62]; layer-1 reads kb0/kb1 straight from B0s (A zeroes cols
//    50-63), so layer-0's duplicate ds_write (wBp) is gone and B1s
//    shrinks to [h1 0-49 | bias 62] (LDS 12KB -> 8KB).
// Layout (verified R5-R10): row r = u*4+gate -> lane's f4 acc holds all 4
// gates of one (unit,batch); cell update in-register. B fragments in LDS
// order [k>>3][n][k&7]; ping-pong parities; one barrier/step; layers
// software-pipelined by one step (exact): step t: l0->h0[t], l1->h1[t-1].
// x prefetch 2 steps ahead (xhold), store at top-of-step.

typedef _Float16 half8 __attribute__((ext_vector_type(8)));
typedef float    f4    __attribute__((ext_vector_type(4)));

__device__ __forceinline__ float sigmE_(float u) {   // u = -log2e * v
    return __builtin_amdgcn_rcpf(1.f + __builtin_amdgcn_exp2f(u));
}
__device__ __forceinline__ float tanhE_(float u) {   // u = 2*log2e * v
    return 1.f - 2.f * __builtin_amdgcn_rcpf(1.f + __builtin_amdgcn_exp2f(u));
}
__device__ __forceinline__ float sigm_(float v) {
    return __builtin_amdgcn_rcpf(1.f + __builtin_amdgcn_exp2f(v * (-LOG2E)));
}
__device__ __forceinline__ float tanh_(float v) {
    return 1.f - 2.f * __builtin_amdgcn_rcpf(1.f + __builtin_amdgcn_exp2f(v * (2.f * LOG2E)));
}
// lanes with (lane&15)<8 keep a0; lanes with (lane&15)>=8 take a1 from
// lane^8 (DPP row_ror:8 = 0x128, banks 2,3 -> bank_mask 0xC). One VALU op.
__device__ __forceinline__ float dppmerge_(float a0, float a1) {
    int r = __builtin_amdgcn_update_dpp(__builtin_bit_cast(int, a0),
                                        __builtin_bit_cast(int, a1),
                                        0x128, 0xF, 0xC, false);
    return __builtin_bit_cast(float, r);
}

__launch_bounds__(1024)
__global__ void lstm2_kernel(const float* __restrict__ x,
                             const float* __restrict__ w_ih0, const float* __restrict__ w_hh0,
                             const float* __restrict__ b_ih0, const float* __restrict__ b_hh0,
                             const float* __restrict__ w_ih1, const float* __restrict__ w_hh1,
                             const float* __restrict__ b_ih1, const float* __restrict__ b_hh1,
                             const float* __restrict__ w_out, const float* __restrict__ b_out,
                             float* __restrict__ out)
{
    const int tid   = threadIdx.x;
    const int wv    = tid >> 6;          // 0..15
    const int lane  = tid & 63;
    const int layer = wv >> 3;           // 0 or 1
    const int w8    = wv & 7;
    const int b0    = blockIdx.x * BB;
    // 13 M-tiles per layer over 8 waves: waves 0-4 take 2, waves 5-7 take 1.
    const int t0     = (w8 < 5) ? 2 * w8 : (5 + w8);
    const int ntiles = (w8 < 5) ? 2 : 1;

    // K-space: B0s rows = [h0: 0-49 | x: 50-61 | bias(=1): 62 | pad: 63]
    //          B1s rows = [h1: 0-49 | unused: 50-61 | bias(=1): 62 | pad: 63]
    __shared__ __align__(16) _Float16 B0s[2][64 * 16];
    __shared__ __align__(16) _Float16 B1s[2][64 * 16];

    // ---- step-invariant A fragments (weights, fragment layout, pre-scaled) ----
    const int m = lane & 15;
    const int q = lane >> 4;
    half8 af[2][4];
    #pragma unroll
    for (int s = 0; s < 2; s++) {
        #pragma unroll
        for (int kb = 0; kb < 4; kb++) {
            #pragma unroll
            for (int j = 0; j < 8; j++) {
                float v = 0.f;
                if (s < ntiles && (layer == 1 || kb < 2)) {
                    const int T  = t0 + s;
                    const int u  = T * 4 + (m >> 2);
                    const int g  = m & 3;
                    const int kg = kb * 32 + q * 8 + j;
                    if (u < HH) {
                        const int r = g * HH + u;
                        if (layer == 0) {
                            if      (kg < 50)  v = w_hh0[r * HH + kg];
                            else if (kg < 62)  v = w_ih0[r * BI + (kg - 50)];
                            else if (kg == 62) v = b_ih0[r] + b_hh0[r];
                        } else {
                            if      (kg < 50)               v = w_ih1[r * HH + kg];
                            else if (kg >= 64 && kg < 114)  v = w_hh1[r * HH + (kg - 64)];
                            else if (kg == 126)             v = b_ih1[r] + b_hh1[r];
                        }
                        // fold activation input scale into the weight
                        v *= (g == 2) ? (2.f * LOG2E) : (-LOG2E);
                    }
                }
                af[s][kb][j] = (_Float16)v;
            }
        }
    }

    // ---- init LDS ----
    for (int i = tid; i < 2 * 64 * 16; i += 1024) {
        (&B0s[0][0])[i] = (_Float16)0.f;
        (&B1s[0][0])[i] = (_Float16)0.f;
    }
    __syncthreads();
    if (tid < 16) {                       // bias (ones) row 62, both parities
        B0s[0][7 * 128 + tid * 8 + 6] = (_Float16)1.f;
        B0s[1][7 * 128 + tid * 8 + 6] = (_Float16)1.f;
        B1s[0][7 * 128 + tid * 8 + 6] = (_Float16)1.f;
        B1s[1][7 * 128 + tid * 8 + 6] = (_Float16)1.f;
    }
    const int xb = tid / 12, xi = tid - xb * 12;           // loop-invariant
    const int xrow = 50 + xi;
    const int xoff = (xrow >> 3) * 128 + xb * 8 + (xrow & 7);
    const size_t xbase = ((size_t)(b0 + xb) * TT) * BI + xi;
    if (tid < 96)                          // x[0] -> parity 0
        B0s[0][xoff] = (_Float16)x[xbase];
    __syncthreads();

    // ---- merged update role: lane owns (u_m, bcol) ----
    const int n16  = lane & 15;
    const int slot = n16 >> 3;            // 0: own acc0; 1: partner's acc1
    const int bcol = n16 & 7;
    const int u_m  = (t0 + slot) * 4 + q;
    const bool wvalid = (u_m < HH) && (slot == 0 || ntiles == 2);
    float cm = 0.f;                        // cell state for (u_m, bcol)

    // ---- per-parity pointers (constant-indexed -> folded at compile time) ----
    const _Float16* rd0[2] = { &B0s[0][0] + lane * 8, &B0s[1][0] + lane * 8 };
    const _Float16* rd1[2] = { &B1s[0][0] + lane * 8, &B1s[1][0] + lane * 8 };
    const int offA = (u_m >> 3) * 128 + bcol * 8 + (u_m & 7);   // h row = u_m
    _Float16* wAp[2] = { (layer ? &B1s[0][0] : &B0s[0][0]) + offA,
                         (layer ? &B1s[1][0] : &B0s[1][0]) + offA };
    _Float16* xdp[2] = { &B0s[0][0] + xoff, &B0s[1][0] + xoff };

    const f4 fzero = {0.f, 0.f, 0.f, 0.f};

    // x stream, 2-step-ahead: xhold carries x[t+1] across a full step.
    const float* xq = x + xbase + BI;     // points at x[1]
    float xhold = 0.f;
    if (tid < 96) xhold = *xq;            // preload x[1]
    xq += BI;                             // points at x[2]

// One timestep at compile-time parity P. DOL0/DOL1: layer activity
// (peel boundaries). DOST: store xhold (=x[t+1]) into parity 1-P.
// DOLD: issue load of x[t+2] (consumed next step).
#define STEP(P, DOL0, DOL1, DOST, DOLD)                                       \
  {                                                                           \
    float xnew = 0.f;                                                         \
    if ((DOLD) && tid < 96) xnew = *xq;                                       \
    if ((DOST) && tid < 96) *xdp[1 - (P)] = (_Float16)xhold;                  \
    if ((layer == 0) ? (DOL0) : (DOL1)) {                                     \
      const half8 bf0 = *(const half8*)(rd0[P]);                              \
      const half8 bf1 = *(const half8*)(rd0[P] + 512);                        \
      f4 acc0, acc1 = fzero;                                                  \
      if (layer == 0) {                                                       \
        acc0 = __builtin_amdgcn_mfma_f32_16x16x32_f16(af[0][0], bf0, fzero, 0, 0, 0); \
        acc0 = __builtin_amdgcn_mfma_f32_16x16x32_f16(af[0][1], bf1, acc0, 0, 0, 0);  \
        if (ntiles > 1) {                                                     \
          acc1 = __builtin_amdgcn_mfma_f32_16x16x32_f16(af[1][0], bf0, fzero, 0, 0, 0); \
          acc1 = __builtin_amdgcn_mfma_f32_16x16x32_f16(af[1][1], bf1, acc1, 0, 0, 0);  \
        }                                                                     \
      } else {                                                                \
        const half8 bf2 = *(const half8*)(rd1[P]);                            \
        const half8 bf3 = *(const half8*)(rd1[P] + 512);                      \
        f4 a0  = __builtin_amdgcn_mfma_f32_16x16x32_f16(af[0][0], bf0, fzero, 0, 0, 0); \
        f4 a0b = __builtin_amdgcn_mfma_f32_16x16x32_f16(af[0][1], bf1, fzero, 0, 0, 0); \
        a0  = __builtin_amdgcn_mfma_f32_16x16x32_f16(af[0][2], bf2, a0,  0, 0, 0);      \
        a0b = __builtin_amdgcn_mfma_f32_16x16x32_f16(af[0][3], bf3, a0b, 0, 0, 0);      \
        acc0 = a0 + a0b;                                                      \
        if (ntiles > 1) {                                                     \
          f4 a1  = __builtin_amdgcn_mfma_f32_16x16x32_f16(af[1][0], bf0, fzero, 0, 0, 0); \
          f4 a1b = __builtin_amdgcn_mfma_f32_16x16x32_f16(af[1][1], bf1, fzero, 0, 0, 0); \
          a1  = __builtin_amdgcn_mfma_f32_16x16x32_f16(af[1][2], bf2, a1,  0, 0, 0);      \
          a1b = __builtin_amdgcn_mfma_f32_16x16x32_f16(af[1][3], bf3, a1b, 0, 0, 0);      \
          acc1 = a1 + a1b;                                                    \
        }                                                                     \
      }                                                                       \
      f4 am;                                                                  \
      _Pragma("unroll")                                                       \
      for (int i = 0; i < 4; i++) am[i] = dppmerge_(acc0[i], acc1[i]);        \
      const float iv = sigmE_(am[0]);                                         \
      const float fv = sigmE_(am[1]);                                         \
      const float gv = tanhE_(am[2]);                                         \
      const float ov = sigmE_(am[3]);                                         \
      cm = fv * cm + iv * gv;                                                 \
      const float h = ov * tanh_(cm);                                         \
      if (wvalid) *wAp[1 - (P)] = (_Float16)h;                                \
    }                                                                         \
    if (DOLD) { xhold = xnew; xq += BI; }                                     \
    __syncthreads();                                                          \
  }

    STEP(0, 1, 0, 1, 1)                   // t = 0   (l0 only; store x[1], load x[2])
    STEP(1, 1, 1, 1, 1)                   // t = 1
    #pragma unroll 1
    for (int it = 0; it < 254; ++it) {    // t = 2 .. 509
        STEP(0, 1, 1, 1, 1)
        STEP(1, 1, 1, 1, 1)
    }
    STEP(0, 1, 1, 1, 0)                   // t = 510 (store x[511], no more loads)
    STEP(1, 1, 1, 0, 0)                   // t = 511
    STEP(0, 0, 1, 0, 0)                   // t = 512 (l1 only)
#undef STEP

    // ---- epilogue: sigmoid(h1[TT-1] . w_out + b_out); h1[TT-1] in parity 1 ----
    if (tid < BB) {
        float s = b_out[0];
        #pragma unroll
        for (int u = 0; u < HH; u++) {
            s += w_out[u] * (float)B1s[1][(u >> 3) * 128 + tid * 8 + (u & 7)];
        }
        out[b0 + tid] = sigm_(s);
    }
}

extern "C" void kernel_launch(void* const* d_in, const int* in_sizes, int n_in,
                              void* d_out, int out_size, void* d_ws, size_t ws_size,
                              hipStream_t stream) {
    const float* x     = (const float*)d_in[0];
    const float* w_ih0 = (const float*)d_in[1];
    const float* w_hh0 = (const float*)d_in[2];
    const float* b_ih0 = (const float*)d_in[3];
    const float* b_hh0 = (const float*)d_in[4];
    const float* w_ih1 = (const float*)d_in[5];
    const float* w_hh1 = (const float*)d_in[6];
    const float* b_ih1 = (const float*)d_in[7];
    const float* b_hh1 = (const float*)d_in[8];
    const float* w_out = (const float*)d_in[9];
    const float* b_out = (const float*)d_in[10];
    float* out = (float*)d_out;

    dim3 grid(BTOT / BB);   // 256 blocks -> 1 per CU
    dim3 block(1024);       // 16 waves: 8 layer-0 + 8 layer-1
    lstm2_kernel<<<grid, block, 0, stream>>>(x, w_ih0, w_hh0, b_ih0, b_hh0,
                                             w_ih1, w_hh1, b_ih1, b_hh1,
                                             w_out, b_out, out);
}